// Round 8
// baseline (119.803 us; speedup 1.0000x reference)
//
#include <hip/hip_runtime.h>
#include <hip/hip_bf16.h>

using bf16x8 = __attribute__((ext_vector_type(8))) __bf16;
using f32x4  = __attribute__((ext_vector_type(4))) float;
using f32x16 = __attribute__((ext_vector_type(16))) float;
using i32x4  = __attribute__((ext_vector_type(4))) int;

#define MFMA_16x16x32(a, b, c) __builtin_amdgcn_mfma_f32_16x16x32_bf16((a), (b), (c), 0, 0, 0)
#define MFMA32(a, b, c)        __builtin_amdgcn_mfma_f32_32x32x16_bf16((a), (b), (c), 0, 0, 0)

__device__ __forceinline__ ushort f2bf(float f) {
    return __builtin_bit_cast(ushort, (__bf16)f);
}
__device__ __forceinline__ unsigned pk_bf16(float lo, float hi) {
    unsigned r;
    asm volatile("v_cvt_pk_bf16_f32 %0, %1, %2" : "=v"(r) : "v"(lo), "v"(hi));
    return r;
}
__device__ __forceinline__ void pl32_swap(unsigned &a, unsigned &b) {
    asm volatile("v_permlane32_swap_b32 %0, %1" : "+v"(a), "+v"(b));
}

// ---------------------------------------------------------------------------
// fp32 -> bf16 vectorized convert (8 elems/thread)
// ---------------------------------------------------------------------------
__global__ __launch_bounds__(256) void cvt_bf16(
    const float* __restrict__ in, ushort* __restrict__ out, int n)
{
    const int i = (blockIdx.x * 256 + threadIdx.x) * 8;
    if (i + 8 <= n) {
        const f32x4 a = *(const f32x4*)(in + i);
        const f32x4 b = *(const f32x4*)(in + i + 4);
        union { ushort u[8]; i32x4 w; } p;
        #pragma unroll
        for (int j = 0; j < 4; ++j) { p.u[j] = f2bf(a[j]); p.u[4 + j] = f2bf(b[j]); }
        *(i32x4*)(out + i) = p.w;
    }
}

// ---------------------------------------------------------------------------
// 3x QKV weights fp32 -> bf16, concat into wbf[3][512*512]
// ---------------------------------------------------------------------------
__global__ __launch_bounds__(256) void cvt_w3(
    const float* __restrict__ w0, const float* __restrict__ w1,
    const float* __restrict__ w2, ushort* __restrict__ out)
{
    const int i = (blockIdx.x * 256 + threadIdx.x) * 8;   // < 3*262144
    const int w = i >> 18, off = i & 262143;
    const float* src = (w == 0) ? w0 : ((w == 1) ? w1 : w2);
    const f32x4 a = *(const f32x4*)(src + off);
    const f32x4 b = *(const f32x4*)(src + off + 4);
    union { ushort u[8]; i32x4 v; } p;
    #pragma unroll
    for (int j = 0; j < 4; ++j) { p.u[j] = f2bf(a[j]); p.u[4 + j] = f2bf(b[j]); }
    *(i32x4*)(out + i) = p.v;
}

// ---------------------------------------------------------------------------
// Fused QKV GEMM: C[M,512] = A[M,512](bf16) * Wbf[512,512](bf16)^T * scale
// blockIdx.y: (y>>2) selects {Wq,Wk,Wv}; (y&3) is the 128-col n-tile.
// q,k -> bf16 head-interleaved [b,h,t,64]; v -> TRANSPOSED [b,h,d,2048]
// ---------------------------------------------------------------------------
__global__ __launch_bounds__(256) void gemm_qkv3(
    const ushort* __restrict__ A, const ushort* __restrict__ Wbf,
    float qscale, ushort* __restrict__ qb, ushort* __restrict__ kb,
    ushort* __restrict__ vb)
{
    __shared__ ushort lA[128][40];
    __shared__ ushort lB[128][40];
    const int wsel = blockIdx.y >> 2;
    const int n0 = (blockIdx.y & 3) * 128;
    const ushort* W = Wbf + wsel * 262144;
    ushort* out = (wsel == 0) ? qb : ((wsel == 1) ? kb : vb);
    const float scale = (wsel == 0) ? qscale : 1.0f;

    const int m0 = blockIdx.x * 128;
    const int tid  = threadIdx.x;
    const int lane = tid & 63;
    const int wave = tid >> 6;
    const int wr = (wave >> 1) * 64, wc = (wave & 1) * 64;
    const int frow = lane & 15, fk = (lane >> 4) * 8;
    const int sr = tid >> 1, scc = (tid & 1) * 16;

    f32x4 acc[4][4] = {};

    for (int k0 = 0; k0 < 512; k0 += 32) {
        const ushort* pa = A + (m0 + sr) * 512 + k0 + scc;
        const i32x4 va0 = *(const i32x4*)(pa);
        const i32x4 va1 = *(const i32x4*)(pa + 8);
        const ushort* pb = W + (n0 + sr) * 512 + k0 + scc;
        const i32x4 vb0 = *(const i32x4*)(pb);
        const i32x4 vb1 = *(const i32x4*)(pb + 8);
        __syncthreads();
        *(i32x4*)&lA[sr][scc]     = va0;
        *(i32x4*)&lA[sr][scc + 8] = va1;
        *(i32x4*)&lB[sr][scc]     = vb0;
        *(i32x4*)&lB[sr][scc + 8] = vb1;
        __syncthreads();

        bf16x8 af[4], bg[4];
        #pragma unroll
        for (int m = 0; m < 4; ++m) af[m] = *(const bf16x8*)&lA[wr + m * 16 + frow][fk];
        #pragma unroll
        for (int n = 0; n < 4; ++n) bg[n] = *(const bf16x8*)&lB[wc + n * 16 + frow][fk];
        #pragma unroll
        for (int m = 0; m < 4; ++m)
            #pragma unroll
            for (int n = 0; n < 4; ++n)
                acc[m][n] = MFMA_16x16x32(af[m], bg[n], acc[m][n]);
    }

    const int rbase = (lane >> 4) * 4;
    const int ccol  = lane & 15;
    if (wsel == 2) {
        // V transposed: vt[((b*8+h)*64 + d)*2048 + t], pack 4 consecutive t
        #pragma unroll
        for (int m = 0; m < 4; ++m)
            #pragma unroll
            for (int n = 0; n < 4; ++n) {
                const int col = n0 + wc + n * 16 + ccol;
                const int row0 = m0 + wr + m * 16 + rbase;
                unsigned long long u = 0;
                #pragma unroll
                for (int r = 0; r < 4; ++r)
                    u |= ((unsigned long long)f2bf(acc[m][n][r])) << (16 * r);
                const size_t idx = ((size_t)((row0 >> 11) * 8 + (col >> 6)) * 64
                                    + (col & 63)) * 2048 + (row0 & 2047);
                *(unsigned long long*)(out + idx) = u;
            }
    } else {
        #pragma unroll
        for (int m = 0; m < 4; ++m)
            #pragma unroll
            for (int n = 0; n < 4; ++n) {
                const int col = n0 + wc + n * 16 + ccol;
                #pragma unroll
                for (int r = 0; r < 4; ++r) {
                    const int row = m0 + wr + m * 16 + rbase + r;
                    out[(((row >> 11) * 8 + (col >> 6)) * 2048 + (row & 2047)) * 64 + (col & 63)]
                        = f2bf(acc[m][n][r] * scale);
                }
            }
    }
}

// ---------------------------------------------------------------------------
// Output GEMM: C[M,512](fp32) = A[M,512](bf16, head-interleaved) * Wp^T + bp
// ---------------------------------------------------------------------------
__global__ __launch_bounds__(256) void gemm_out(
    const ushort* __restrict__ A, const float* __restrict__ W,
    const float* __restrict__ bias, float* __restrict__ out)
{
    __shared__ ushort lA[128][40];
    __shared__ ushort lB[128][40];
    const int m0 = blockIdx.x * 128;
    const int n0 = blockIdx.y * 128;
    const int tid  = threadIdx.x;
    const int lane = tid & 63;
    const int wave = tid >> 6;
    const int wr = (wave >> 1) * 64, wc = (wave & 1) * 64;
    const int frow = lane & 15, fk = (lane >> 4) * 8;
    const int sr = tid >> 1, scc = (tid & 1) * 16;

    f32x4 acc[4][4] = {};

    for (int k0 = 0; k0 < 512; k0 += 32) {
        const int row = m0 + sr, c = k0 + scc;
        const ushort* pa = A + ((((row >> 11) * 8 + (c >> 6)) * 2048 + (row & 2047)) * 64 + (c & 63));
        const i32x4 va0 = *(const i32x4*)(pa);
        const i32x4 va1 = *(const i32x4*)(pa + 8);
        const float* pb = W + (n0 + sr) * 512 + k0 + scc;
        const f32x4 b0 = *(const f32x4*)(pb);
        const f32x4 b1 = *(const f32x4*)(pb + 4);
        const f32x4 b2 = *(const f32x4*)(pb + 8);
        const f32x4 b3 = *(const f32x4*)(pb + 12);
        union { ushort u[16]; i32x4 w[2]; } pB;
        #pragma unroll
        for (int j = 0; j < 4; ++j) {
            pB.u[j]      = f2bf(b0[j]);  pB.u[4 + j]  = f2bf(b1[j]);
            pB.u[8 + j]  = f2bf(b2[j]);  pB.u[12 + j] = f2bf(b3[j]);
        }
        __syncthreads();
        *(i32x4*)&lA[sr][scc]     = va0;
        *(i32x4*)&lA[sr][scc + 8] = va1;
        *(i32x4*)&lB[sr][scc]     = pB.w[0];
        *(i32x4*)&lB[sr][scc + 8] = pB.w[1];
        __syncthreads();

        bf16x8 af[4], bg[4];
        #pragma unroll
        for (int m = 0; m < 4; ++m) af[m] = *(const bf16x8*)&lA[wr + m * 16 + frow][fk];
        #pragma unroll
        for (int n = 0; n < 4; ++n) bg[n] = *(const bf16x8*)&lB[wc + n * 16 + frow][fk];
        #pragma unroll
        for (int m = 0; m < 4; ++m)
            #pragma unroll
            for (int n = 0; n < 4; ++n)
                acc[m][n] = MFMA_16x16x32(af[m], bg[n], acc[m][n]);
    }

    const int rbase = (lane >> 4) * 4;
    const int ccol  = lane & 15;
    #pragma unroll
    for (int m = 0; m < 4; ++m)
        #pragma unroll
        for (int n = 0; n < 4; ++n) {
            const int col = n0 + wc + n * 16 + ccol;
            const float bv = bias[col];
            #pragma unroll
            for (int r = 0; r < 4; ++r) {
                const int row = m0 + wr + m * 16 + rbase + r;
                out[row * 512 + col] = acc[m][n][r] + bv;
            }
        }
}

// ---------------------------------------------------------------------------
// Causal flash attention R8: 2 waves x 64 q-rows per block (1024 blocks,
// ~all-resident), K/V shared via LDS double-buffer (XOR-swizzled), per-wave
// swapped-QK^T 32x32 in-register softmax (math unchanged since R5).
// q,k: [bh][t][64]; vt: [bh][d][2048] bf16.
// ---------------------------------------------------------------------------
__global__ __launch_bounds__(128) void attn_kernel(
    const ushort* __restrict__ q, const ushort* __restrict__ k,
    const ushort* __restrict__ vt, ushort* __restrict__ att)
{
    __shared__ ushort lK[2][64][64];    // [buf][s_local][d], XOR-swizzled groups
    __shared__ ushort lV[2][64][64];    // [buf][d][s_local], XOR-swizzled groups

    // snake pairing: with ~all blocks resident, a CU's blocks sum to ~const work
    const int NB   = (int)(gridDim.x * gridDim.y);   // 1024
    const int NH   = (int)gridDim.y;                 // 32 bh slices
    const int half = NB >> 1;
    const int n    = (int)(blockIdx.y * gridDim.x + blockIdx.x);
    const int r    = (n < half) ? n : (NB - 1 - (n - half));
    const int qt0  = ((int)gridDim.x - 1 - r / NH) * 64;   // heavy-first
    const int bh   = r % NH;

    const ushort* Q  = q  + (size_t)bh * 2048 * 64;
    const ushort* K  = k  + (size_t)bh * 2048 * 64;
    const ushort* VT = vt + (size_t)bh * 2048 * 64;
    ushort* O = att + (size_t)bh * 2048 * 64;

    const int tid = threadIdx.x;
    const int wv  = tid >> 6;
    const int l   = tid & 63;
    const int ql  = l & 31;
    const int hi  = l >> 5;
    const int wrow0 = qt0 + wv * 32;     // wave's first q-row
    const int qrow  = wrow0 + ql;
    const int wmax  = wrow0 + 31;
    const int qkey  = ql & 7;
    const float LOG2E = 1.44269504088896f;

    // staging map: 128 threads, thread -> (row, 4 groups of 8 elems)
    const int srow = tid >> 1;
    const int sg   = (tid & 1) * 4;
    const int skey = srow & 7;

    bf16x8 aq[4];
    #pragma unroll
    for (int kk = 0; kk < 4; ++kk)
        aq[kk] = *(const bf16x8*)(Q + (size_t)qrow * 64 + kk * 16 + hi * 8);

    f32x16 o0 = {}, o1 = {};
    float mrun = -30000.0f, lrun = 0.0f;
    const int nt = qt0 / 64 + 1;

    i32x4 kr[4], vr[4];                  // staging registers
    auto loadG = [&](int s0) {
        const ushort* kp = K + (size_t)(s0 + srow) * 64 + sg * 8;
        const ushort* vp = VT + (size_t)srow * 2048 + s0 + sg * 8;
        #pragma unroll
        for (int j = 0; j < 4; ++j) {
            kr[j] = *(const i32x4*)(kp + j * 8);
            vr[j] = *(const i32x4*)(vp + j * 8);
        }
    };
    auto writeL = [&](int b) {
        #pragma unroll
        for (int j = 0; j < 4; ++j) {
            *(i32x4*)&lK[b][srow][((sg + j) ^ skey) * 8] = kr[j];
            *(i32x4*)&lV[b][srow][((sg + j) ^ skey) * 8] = vr[j];
        }
    };

    loadG(0);
    writeL(0);
    if (nt > 1) loadG(64);               // tile 1 in regs across iter 0

    for (int t = 0; t < nt; ++t) {
        const int p  = t & 1;
        const int s0 = t * 64;
        __syncthreads();                  // buf[p] visible; buf[p^1] drained
        if (t + 1 < nt) writeL(p ^ 1);    // regs (tile t+1) -> LDS
        if (t + 2 < nt) loadG(s0 + 128);  // issue tile t+2, lands next iter

        if (s0 > wmax) continue;          // fully-masked tile for this wave

        // S^T = K * Q^T from LDS (swizzled reads)
        f32x16 sa = {}, sb = {};
        #pragma unroll
        for (int kk = 0; kk < 4; ++kk) {
            const bf16x8 kb0 = *(const bf16x8*)&lK[p][ql]     [((2 * kk + hi) ^ qkey) * 8];
            const bf16x8 kb1 = *(const bf16x8*)&lK[p][32 + ql][((2 * kk + hi) ^ qkey) * 8];
            sa = MFMA32(kb0, aq[kk], sa);
            sb = MFMA32(kb1, aq[kk], sb);
        }

        if (s0 + 63 > wrow0) {            // tile intersects this wave's diagonal
            #pragma unroll
            for (int rr = 0; rr < 16; ++rr) {
                const int cr = (rr & 3) + 8 * (rr >> 2) + 4 * hi;
                if (s0 + cr > qrow)      sa[rr] = -30000.0f;
                if (s0 + 32 + cr > qrow) sb[rr] = -30000.0f;
            }
        }

        // row max (lane-local rows): 31 fmax + 1 cross-half shuffle
        float pmax = sa[0];
        #pragma unroll
        for (int rr = 1; rr < 16; ++rr) pmax = fmaxf(pmax, sa[rr]);
        #pragma unroll
        for (int rr = 0; rr < 16; ++rr) pmax = fmaxf(pmax, sb[rr]);
        pmax = fmaxf(pmax, __shfl_xor(pmax, 32));

        // defer-max (T13)
        if (__any(pmax > mrun + 8.0f)) {
            const float mnew  = fmaxf(mrun, pmax);
            const float alpha = exp2f((mrun - mnew) * LOG2E);
            mrun = mnew;
            lrun *= alpha;
            #pragma unroll
            for (int rr = 0; rr < 16; ++rr) {
                const float ar = __shfl(alpha, (rr & 3) + 8 * (rr >> 2) + 4 * hi);
                o0[rr] *= ar; o1[rr] *= ar;
            }
        }

        const float mb = mrun * LOG2E;
        float ps = 0.0f;
        #pragma unroll
        for (int rr = 0; rr < 16; ++rr) {
            sa[rr] = exp2f(fmaf(sa[rr], LOG2E, -mb));
            sb[rr] = exp2f(fmaf(sb[rr], LOG2E, -mb));
            ps += sa[rr] + sb[rr];
        }
        ps += __shfl_xor(ps, 32);
        lrun += ps;

        // P -> PV A-fragments (T12)
        unsigned paw[4][4];
        #pragma unroll
        for (int ks = 0; ks < 4; ++ks) {
            const int e = 2 * ks, f = 2 * ks + 1;
            const int ra = 4 * (e & 3), rb = 4 * (f & 3);
            unsigned A0, A1, B0, B1;
            if (e >> 2) { A0 = pk_bf16(sb[ra], sb[ra + 1]); A1 = pk_bf16(sb[ra + 2], sb[ra + 3]); }
            else        { A0 = pk_bf16(sa[ra], sa[ra + 1]); A1 = pk_bf16(sa[ra + 2], sa[ra + 3]); }
            if (f >> 2) { B0 = pk_bf16(sb[rb], sb[rb + 1]); B1 = pk_bf16(sb[rb + 2], sb[rb + 3]); }
            else        { B0 = pk_bf16(sa[rb], sa[rb + 1]); B1 = pk_bf16(sa[rb + 2], sa[rb + 3]); }
            pl32_swap(A0, B0);
            pl32_swap(A1, B1);
            paw[ks][0] = A0; paw[ks][1] = A1; paw[ks][2] = B0; paw[ks][3] = B1;
        }

        // O += P * V from LDS V^T tile (swizzled reads)
        #pragma unroll
        for (int ks = 0; ks < 4; ++ks) {
            union { unsigned w[4]; bf16x8 v; } u;
            u.w[0] = paw[ks][0]; u.w[1] = paw[ks][1];
            u.w[2] = paw[ks][2]; u.w[3] = paw[ks][3];
            const bf16x8 v0 = *(const bf16x8*)&lV[p][ql]     [((2 * ks + hi) ^ qkey) * 8];
            const bf16x8 v1 = *(const bf16x8*)&lV[p][32 + ql][((2 * ks + hi) ^ qkey) * 8];
            o0 = MFMA32(u.v, v0, o0);
            o1 = MFMA32(u.v, v1, o1);
        }
    }

    // epilogue
    const float linv = 1.0f / fmaxf(lrun, 1e-30f);
    #pragma unroll
    for (int rr = 0; rr < 16; ++rr) {
        const int cr = (rr & 3) + 8 * (rr >> 2) + 4 * hi;
        const float li = __shfl(linv, cr);
        const int row = wrow0 + cr;
        O[(size_t)row * 64 + ql]      = f2bf(o0[rr] * li);
        O[(size_t)row * 64 + 32 + ql] = f2bf(o1[rr] * li);
    }
}

extern "C" void kernel_launch(void* const* d_in, const int* in_sizes, int n_in,
                              void* d_out, int out_size, void* d_ws, size_t ws_size,
                              hipStream_t stream) {
    const float* x  = (const float*)d_in[0];   // x_q  [4,2048,512] fp32
    const float* Wq = (const float*)d_in[1];   // [8,64,512] fp32
    const float* Wk = (const float*)d_in[2];
    const float* Wv = (const float*)d_in[3];
    const float* Wp = (const float*)d_in[4];   // [512,512] fp32
    const float* bp = (const float*)d_in[5];   // [512] fp32
    float* out = (float*)d_out;                // [4,2048,512] fp32

    const size_t NEL  = 4u * 8u * 2048u * 64u;   // 4,194,304 (all batches)
    const size_t NELB = 8u * 2048u * 64u;        // 1,048,576 (one batch)
    const float qscale = 0.04419417382415922f;   // 512^-0.5 folded into q

    if (ws_size >= 3u * NEL * sizeof(ushort)) {
        // d_out bytes: [xbf (bf16 x)][qb (bf16 q)] — final GEMM overwrites.
        // wbf (bf16 QKV weights) parks at ab; attn overwrites ab only later.
        ushort* xbf = (ushort*)d_out;
        ushort* qb  = xbf + NEL;
        ushort* kb  = (ushort*)d_ws;
        ushort* vb  = kb + NEL;                  // holds VT [b,h,d,2048]
        ushort* ab  = vb + NEL;
        ushort* wbf = ab;                        // 3*262144 ushorts = 1.5 MB
        hipLaunchKernelGGL(cvt_bf16, dim3((int)(NEL / (256 * 8))), dim3(256), 0, stream,
                           x, xbf, (int)NEL);
        hipLaunchKernelGGL(cvt_w3, dim3(384), dim3(256), 0, stream, Wq, Wk, Wv, wbf);
        hipLaunchKernelGGL(gemm_qkv3, dim3(64, 12), dim3(256), 0, stream,
                           xbf, wbf, qscale, qb, kb, vb);
        hipLaunchKernelGGL(attn_kernel, dim3(32, 32), dim3(128), 0, stream, qb, kb, vb, ab);
        hipLaunchKernelGGL(gemm_out, dim3(64, 4), dim3(256), 0, stream, ab, Wp, bp, out);
    } else {
        // per-batch fallback: ws need = 3 * NELB * 2 = 6.3 MB
        ushort* kb = (ushort*)d_ws;
        ushort* vb = kb + NELB;
        ushort* ab = vb + NELB;
        ushort* wbf = ab;                        // 1.5 MB <= 2 MB slice
        for (int b = 0; b < 4; ++b) {
            const float* xb = x + (size_t)b * 2048u * 512u;
            float* ob = out + (size_t)b * 2048u * 512u;
            ushort* xbf = (ushort*)ob;           // batch slice: [xbf][qb]
            ushort* qb  = xbf + NELB;
            hipLaunchKernelGGL(cvt_bf16, dim3((int)(NELB / (256 * 8))), dim3(256), 0, stream,
                               xb, xbf, (int)NELB);
            hipLaunchKernelGGL(cvt_w3, dim3(384), dim3(256), 0, stream, Wq, Wk, Wv, wbf);
            hipLaunchKernelGGL(gemm_qkv3, dim3(16, 12), dim3(256), 0, stream,
                               xbf, wbf, qscale, qb, kb, vb);
            hipLaunchKernelGGL(attn_kernel, dim3(32, 8), dim3(128), 0, stream, qb, kb, vb, ab);
            hipLaunchKernelGGL(gemm_out, dim3(16, 4), dim3(256), 0, stream, ab, Wp, bp, ob);
        }
    }
}

// Round 9
// 106.474 us; speedup vs baseline: 1.1252x; 1.1252x over previous
//
#include <hip/hip_runtime.h>
#include <hip/hip_bf16.h>

using bf16x8 = __attribute__((ext_vector_type(8))) __bf16;
using f32x4  = __attribute__((ext_vector_type(4))) float;
using f32x16 = __attribute__((ext_vector_type(16))) float;
using i32x4  = __attribute__((ext_vector_type(4))) int;

#define MFMA_16x16x32(a, b, c) __builtin_amdgcn_mfma_f32_16x16x32_bf16((a), (b), (c), 0, 0, 0)
#define MFMA32(a, b, c)        __builtin_amdgcn_mfma_f32_32x32x16_bf16((a), (b), (c), 0, 0, 0)

__device__ __forceinline__ ushort f2bf(float f) {
    return __builtin_bit_cast(ushort, (__bf16)f);
}
__device__ __forceinline__ unsigned pk_bf16(float lo, float hi) {
    unsigned r;
    asm volatile("v_cvt_pk_bf16_f32 %0, %1, %2" : "=v"(r) : "v"(lo), "v"(hi));
    return r;
}
__device__ __forceinline__ void pl32_swap(unsigned &a, unsigned &b) {
    asm volatile("v_permlane32_swap_b32 %0, %1" : "+v"(a), "+v"(b));
}

// ---------------------------------------------------------------------------
// fp32 -> bf16 vectorized convert (8 elems/thread)
// ---------------------------------------------------------------------------
__global__ __launch_bounds__(256) void cvt_bf16(
    const float* __restrict__ in, ushort* __restrict__ out, int n)
{
    const int i = (blockIdx.x * 256 + threadIdx.x) * 8;
    if (i + 8 <= n) {
        const f32x4 a = *(const f32x4*)(in + i);
        const f32x4 b = *(const f32x4*)(in + i + 4);
        union { ushort u[8]; i32x4 w; } p;
        #pragma unroll
        for (int j = 0; j < 4; ++j) { p.u[j] = f2bf(a[j]); p.u[4 + j] = f2bf(b[j]); }
        *(i32x4*)(out + i) = p.w;
    }
}

// ---------------------------------------------------------------------------
// 3x QKV weights fp32 -> bf16, concat into wbf[3][512*512]
// ---------------------------------------------------------------------------
__global__ __launch_bounds__(256) void cvt_w3(
    const float* __restrict__ w0, const float* __restrict__ w1,
    const float* __restrict__ w2, ushort* __restrict__ out)
{
    const int i = (blockIdx.x * 256 + threadIdx.x) * 8;   // < 3*262144
    const int w = i >> 18, off = i & 262143;
    const float* src = (w == 0) ? w0 : ((w == 1) ? w1 : w2);
    const f32x4 a = *(const f32x4*)(src + off);
    const f32x4 b = *(const f32x4*)(src + off + 4);
    union { ushort u[8]; i32x4 v; } p;
    #pragma unroll
    for (int j = 0; j < 4; ++j) { p.u[j] = f2bf(a[j]); p.u[4 + j] = f2bf(b[j]); }
    *(i32x4*)(out + i) = p.v;
}

// ---------------------------------------------------------------------------
// Fused QKV GEMM (pipelined staging): C = A(bf16) * Wbf(bf16)^T * scale
// blockIdx.y: (y>>2) selects {Wq,Wk,Wv}; (y&3) is the 128-col n-tile.
// q,k -> bf16 head-interleaved [b,h,t,64]; v -> TRANSPOSED [b,h,d,2048]
// ---------------------------------------------------------------------------
__global__ __launch_bounds__(256) void gemm_qkv3(
    const ushort* __restrict__ A, const ushort* __restrict__ Wbf,
    float qscale, ushort* __restrict__ qb, ushort* __restrict__ kb,
    ushort* __restrict__ vb)
{
    __shared__ ushort lA[128][40];
    __shared__ ushort lB[128][40];
    const int wsel = blockIdx.y >> 2;
    const int n0 = (blockIdx.y & 3) * 128;
    const ushort* W = Wbf + wsel * 262144;
    ushort* out = (wsel == 0) ? qb : ((wsel == 1) ? kb : vb);
    const float scale = (wsel == 0) ? qscale : 1.0f;

    const int m0 = blockIdx.x * 128;
    const int tid  = threadIdx.x;
    const int lane = tid & 63;
    const int wave = tid >> 6;
    const int wr = (wave >> 1) * 64, wc = (wave & 1) * 64;
    const int frow = lane & 15, fk = (lane >> 4) * 8;
    const int sr = tid >> 1, scc = (tid & 1) * 16;

    f32x4 acc[4][4] = {};
    i32x4 va0, va1, vb0, vb1;
    auto load = [&](int k0) {
        const ushort* pa = A + (m0 + sr) * 512 + k0 + scc;
        va0 = *(const i32x4*)(pa);
        va1 = *(const i32x4*)(pa + 8);
        const ushort* pb = W + (n0 + sr) * 512 + k0 + scc;
        vb0 = *(const i32x4*)(pb);
        vb1 = *(const i32x4*)(pb + 8);
    };

    load(0);
    for (int t = 0; t < 16; ++t) {
        __syncthreads();                       // prior step's LDS reads done
        *(i32x4*)&lA[sr][scc]     = va0;
        *(i32x4*)&lA[sr][scc + 8] = va1;
        *(i32x4*)&lB[sr][scc]     = vb0;
        *(i32x4*)&lB[sr][scc + 8] = vb1;
        if (t + 1 < 16) load((t + 1) * 32);    // next step hides under compute
        __syncthreads();

        bf16x8 af[4], bg[4];
        #pragma unroll
        for (int m = 0; m < 4; ++m) af[m] = *(const bf16x8*)&lA[wr + m * 16 + frow][fk];
        #pragma unroll
        for (int n = 0; n < 4; ++n) bg[n] = *(const bf16x8*)&lB[wc + n * 16 + frow][fk];
        #pragma unroll
        for (int m = 0; m < 4; ++m)
            #pragma unroll
            for (int n = 0; n < 4; ++n)
                acc[m][n] = MFMA_16x16x32(af[m], bg[n], acc[m][n]);
    }

    const int rbase = (lane >> 4) * 4;
    const int ccol  = lane & 15;
    if (wsel == 2) {
        // V transposed: vt[((b*8+h)*64 + d)*2048 + t], pack 4 consecutive t
        #pragma unroll
        for (int m = 0; m < 4; ++m)
            #pragma unroll
            for (int n = 0; n < 4; ++n) {
                const int col = n0 + wc + n * 16 + ccol;
                const int row0 = m0 + wr + m * 16 + rbase;
                unsigned long long u = 0;
                #pragma unroll
                for (int r = 0; r < 4; ++r)
                    u |= ((unsigned long long)f2bf(acc[m][n][r])) << (16 * r);
                const size_t idx = ((size_t)((row0 >> 11) * 8 + (col >> 6)) * 64
                                    + (col & 63)) * 2048 + (row0 & 2047);
                *(unsigned long long*)(out + idx) = u;
            }
    } else {
        #pragma unroll
        for (int m = 0; m < 4; ++m)
            #pragma unroll
            for (int n = 0; n < 4; ++n) {
                const int col = n0 + wc + n * 16 + ccol;
                #pragma unroll
                for (int r = 0; r < 4; ++r) {
                    const int row = m0 + wr + m * 16 + rbase + r;
                    out[(((row >> 11) * 8 + (col >> 6)) * 2048 + (row & 2047)) * 64 + (col & 63)]
                        = f2bf(acc[m][n][r] * scale);
                }
            }
    }
}

// ---------------------------------------------------------------------------
// Output GEMM (pipelined staging): C[M,512](fp32) = A(bf16, head-il) * Wp^T + bp
// ---------------------------------------------------------------------------
__global__ __launch_bounds__(256) void gemm_out(
    const ushort* __restrict__ A, const float* __restrict__ W,
    const float* __restrict__ bias, float* __restrict__ out)
{
    __shared__ ushort lA[128][40];
    __shared__ ushort lB[128][40];
    const int m0 = blockIdx.x * 128;
    const int n0 = blockIdx.y * 128;
    const int tid  = threadIdx.x;
    const int lane = tid & 63;
    const int wave = tid >> 6;
    const int wr = (wave >> 1) * 64, wc = (wave & 1) * 64;
    const int frow = lane & 15, fk = (lane >> 4) * 8;
    const int sr = tid >> 1, scc = (tid & 1) * 16;

    f32x4 acc[4][4] = {};
    i32x4 va0, va1;
    f32x4 b0, b1, b2, b3;
    auto load = [&](int k0) {
        const int row = m0 + sr, c = k0 + scc;
        const ushort* pa = A + ((((row >> 11) * 8 + (c >> 6)) * 2048 + (row & 2047)) * 64 + (c & 63));
        va0 = *(const i32x4*)(pa);
        va1 = *(const i32x4*)(pa + 8);
        const float* pb = W + (n0 + sr) * 512 + k0 + scc;
        b0 = *(const f32x4*)(pb);
        b1 = *(const f32x4*)(pb + 4);
        b2 = *(const f32x4*)(pb + 8);
        b3 = *(const f32x4*)(pb + 12);
    };

    load(0);
    for (int t = 0; t < 16; ++t) {
        union { ushort u[16]; i32x4 w[2]; } pB;
        #pragma unroll
        for (int j = 0; j < 4; ++j) {
            pB.u[j]      = f2bf(b0[j]);  pB.u[4 + j]  = f2bf(b1[j]);
            pB.u[8 + j]  = f2bf(b2[j]);  pB.u[12 + j] = f2bf(b3[j]);
        }
        __syncthreads();
        *(i32x4*)&lA[sr][scc]     = va0;
        *(i32x4*)&lA[sr][scc + 8] = va1;
        *(i32x4*)&lB[sr][scc]     = pB.w[0];
        *(i32x4*)&lB[sr][scc + 8] = pB.w[1];
        if (t + 1 < 16) load((t + 1) * 32);
        __syncthreads();

        bf16x8 af[4], bg[4];
        #pragma unroll
        for (int m = 0; m < 4; ++m) af[m] = *(const bf16x8*)&lA[wr + m * 16 + frow][fk];
        #pragma unroll
        for (int n = 0; n < 4; ++n) bg[n] = *(const bf16x8*)&lB[wc + n * 16 + frow][fk];
        #pragma unroll
        for (int m = 0; m < 4; ++m)
            #pragma unroll
            for (int n = 0; n < 4; ++n)
                acc[m][n] = MFMA_16x16x32(af[m], bg[n], acc[m][n]);
    }

    const int rbase = (lane >> 4) * 4;
    const int ccol  = lane & 15;
    #pragma unroll
    for (int m = 0; m < 4; ++m)
        #pragma unroll
        for (int n = 0; n < 4; ++n) {
            const int col = n0 + wc + n * 16 + ccol;
            const float bv = bias[col];
            #pragma unroll
            for (int r = 0; r < 4; ++r) {
                const int row = m0 + wr + m * 16 + rbase + r;
                out[row * 512 + col] = acc[m][n][r] + bv;
            }
        }
}

// ---------------------------------------------------------------------------
// Causal flash attention (R7 winning config, byte-identical): 4 waves x 128
// q-rows per block, K/V shared via LDS double-buffer (XOR-swizzled), per-wave
// swapped-QK^T 32x32 in-register softmax. q,k: [bh][t][64]; vt: [bh][d][2048].
// ---------------------------------------------------------------------------
__global__ __launch_bounds__(256, 2) void attn_kernel(
    const ushort* __restrict__ q, const ushort* __restrict__ k,
    const ushort* __restrict__ vt, ushort* __restrict__ att)
{
    __shared__ ushort lK[2][64][64];    // [buf][s_local][d], XOR-swizzled groups
    __shared__ ushort lV[2][64][64];    // [buf][d][s_local], XOR-swizzled groups

    const int NB   = (int)(gridDim.x * gridDim.y);
    const int NH   = NB >> 4;            // number of bh slices (16 q-tiles)
    const int half = NB >> 1;
    const int n    = (int)(blockIdx.y * gridDim.x + blockIdx.x);
    const int r    = (n < half) ? n : (NB - 1 - (n - half));
    const int qt0  = (15 - r / NH) * 128;    // heavy-first
    const int bh   = r % NH;

    const ushort* Q  = q  + (size_t)bh * 2048 * 64;
    const ushort* K  = k  + (size_t)bh * 2048 * 64;
    const ushort* VT = vt + (size_t)bh * 2048 * 64;
    ushort* O = att + (size_t)bh * 2048 * 64;

    const int tid = threadIdx.x;
    const int wv  = tid >> 6;
    const int l   = tid & 63;
    const int ql  = l & 31;
    const int hi  = l >> 5;
    const int wrow0 = qt0 + wv * 32;     // wave's first q-row
    const int qrow  = wrow0 + ql;
    const int wmax  = wrow0 + 31;
    const int qkey  = ql & 7;
    const float LOG2E = 1.44269504088896f;

    // staging map: thread -> (row, 2 groups of 8 elems)
    const int srow = tid >> 2;
    const int sg   = (tid & 3) * 2;
    const int skey = srow & 7;

    bf16x8 aq[4];
    #pragma unroll
    for (int kk = 0; kk < 4; ++kk)
        aq[kk] = *(const bf16x8*)(Q + (size_t)qrow * 64 + kk * 16 + hi * 8);

    f32x16 o0 = {}, o1 = {};
    float mrun = -30000.0f, lrun = 0.0f;
    const int nt = qt0 / 64 + 2;

    i32x4 kr0, kr1, vr0, vr1;            // staging registers
    auto loadG = [&](int s0) {
        const ushort* kp = K + (size_t)(s0 + srow) * 64 + (tid & 3) * 16;
        kr0 = *(const i32x4*)(kp);
        kr1 = *(const i32x4*)(kp + 8);
        const ushort* vp = VT + (size_t)srow * 2048 + s0 + (tid & 3) * 16;
        vr0 = *(const i32x4*)(vp);
        vr1 = *(const i32x4*)(vp + 8);
    };
    auto writeL = [&](int b) {
        *(i32x4*)&lK[b][srow][((sg    ) ^ skey) * 8] = kr0;
        *(i32x4*)&lK[b][srow][((sg + 1) ^ skey) * 8] = kr1;
        *(i32x4*)&lV[b][srow][((sg    ) ^ skey) * 8] = vr0;
        *(i32x4*)&lV[b][srow][((sg + 1) ^ skey) * 8] = vr1;
    };

    loadG(0);
    writeL(0);
    if (nt > 1) loadG(64);               // tile 1 in regs across iter 0

    for (int t = 0; t < nt; ++t) {
        const int p  = t & 1;
        const int s0 = t * 64;
        __syncthreads();                  // buf[p] visible; buf[p^1] drained
        if (t + 1 < nt) writeL(p ^ 1);    // regs (tile t+1) -> LDS
        if (t + 2 < nt) loadG(s0 + 128);  // issue tile t+2, lands next iter

        if (s0 > wmax) continue;          // fully-masked tile for this wave

        // S^T = K * Q^T from LDS (swizzled reads)
        f32x16 sa = {}, sb = {};
        #pragma unroll
        for (int kk = 0; kk < 4; ++kk) {
            const bf16x8 kb0 = *(const bf16x8*)&lK[p][ql]     [((2 * kk + hi) ^ qkey) * 8];
            const bf16x8 kb1 = *(const bf16x8*)&lK[p][32 + ql][((2 * kk + hi) ^ qkey) * 8];
            sa = MFMA32(kb0, aq[kk], sa);
            sb = MFMA32(kb1, aq[kk], sb);
        }

        if (s0 + 63 > wrow0) {            // tile intersects this wave's diagonal
            #pragma unroll
            for (int rr = 0; rr < 16; ++rr) {
                const int cr = (rr & 3) + 8 * (rr >> 2) + 4 * hi;
                if (s0 + cr > qrow)      sa[rr] = -30000.0f;
                if (s0 + 32 + cr > qrow) sb[rr] = -30000.0f;
            }
        }

        // row max (lane-local rows): 31 fmax + 1 cross-half shuffle
        float pmax = sa[0];
        #pragma unroll
        for (int rr = 1; rr < 16; ++rr) pmax = fmaxf(pmax, sa[rr]);
        #pragma unroll
        for (int rr = 0; rr < 16; ++rr) pmax = fmaxf(pmax, sb[rr]);
        pmax = fmaxf(pmax, __shfl_xor(pmax, 32));

        // defer-max (T13)
        if (__any(pmax > mrun + 8.0f)) {
            const float mnew  = fmaxf(mrun, pmax);
            const float alpha = exp2f((mrun - mnew) * LOG2E);
            mrun = mnew;
            lrun *= alpha;
            #pragma unroll
            for (int rr = 0; rr < 16; ++rr) {
                const float ar = __shfl(alpha, (rr & 3) + 8 * (rr >> 2) + 4 * hi);
                o0[rr] *= ar; o1[rr] *= ar;
            }
        }

        const float mb = mrun * LOG2E;
        float ps = 0.0f;
        #pragma unroll
        for (int rr = 0; rr < 16; ++rr) {
            sa[rr] = exp2f(fmaf(sa[rr], LOG2E, -mb));
            sb[rr] = exp2f(fmaf(sb[rr], LOG2E, -mb));
            ps += sa[rr] + sb[rr];
        }
        ps += __shfl_xor(ps, 32);
        lrun += ps;

        // P -> PV A-fragments (T12)
        unsigned paw[4][4];
        #pragma unroll
        for (int ks = 0; ks < 4; ++ks) {
            const int e = 2 * ks, f = 2 * ks + 1;
            const int ra = 4 * (e & 3), rb = 4 * (f & 3);
            unsigned A0, A1, B0, B1;
            if (e >> 2) { A0 = pk_bf16(sb[ra], sb[ra + 1]); A1 = pk_bf16(sb[ra + 2], sb[ra + 3]); }
            else        { A0 = pk_bf16(sa[ra], sa[ra + 1]); A1 = pk_bf16(sa[ra + 2], sa[ra + 3]); }
            if (f >> 2) { B0 = pk_bf16(sb[rb], sb[rb + 1]); B1 = pk_bf16(sb[rb + 2], sb[rb + 3]); }
            else        { B0 = pk_bf16(sa[rb], sa[rb + 1]); B1 = pk_bf16(sa[rb + 2], sa[rb + 3]); }
            pl32_swap(A0, B0);
            pl32_swap(A1, B1);
            paw[ks][0] = A0; paw[ks][1] = A1; paw[ks][2] = B0; paw[ks][3] = B1;
        }

        // O += P * V from LDS V^T tile (swizzled reads)
        #pragma unroll
        for (int ks = 0; ks < 4; ++ks) {
            union { unsigned w[4]; bf16x8 v; } u;
            u.w[0] = paw[ks][0]; u.w[1] = paw[ks][1];
            u.w[2] = paw[ks][2]; u.w[3] = paw[ks][3];
            const bf16x8 v0 = *(const bf16x8*)&lV[p][ql]     [((2 * ks + hi) ^ qkey) * 8];
            const bf16x8 v1 = *(const bf16x8*)&lV[p][32 + ql][((2 * ks + hi) ^ qkey) * 8];
            o0 = MFMA32(u.v, v0, o0);
            o1 = MFMA32(u.v, v1, o1);
        }
    }

    // epilogue
    const float linv = 1.0f / fmaxf(lrun, 1e-30f);
    #pragma unroll
    for (int rr = 0; rr < 16; ++rr) {
        const int cr = (rr & 3) + 8 * (rr >> 2) + 4 * hi;
        const float li = __shfl(linv, cr);
        const int row = wrow0 + cr;
        O[(size_t)row * 64 + ql]      = f2bf(o0[rr] * li);
        O[(size_t)row * 64 + 32 + ql] = f2bf(o1[rr] * li);
    }
}

extern "C" void kernel_launch(void* const* d_in, const int* in_sizes, int n_in,
                              void* d_out, int out_size, void* d_ws, size_t ws_size,
                              hipStream_t stream) {
    const float* x  = (const float*)d_in[0];   // x_q  [4,2048,512] fp32
    const float* Wq = (const float*)d_in[1];   // [8,64,512] fp32
    const float* Wk = (const float*)d_in[2];
    const float* Wv = (const float*)d_in[3];
    const float* Wp = (const float*)d_in[4];   // [512,512] fp32
    const float* bp = (const float*)d_in[5];   // [512] fp32
    float* out = (float*)d_out;                // [4,2048,512] fp32

    const size_t NEL  = 4u * 8u * 2048u * 64u;   // 4,194,304 (all batches)
    const size_t NELB = 8u * 2048u * 64u;        // 1,048,576 (one batch)
    const float qscale = 0.04419417382415922f;   // 512^-0.5 folded into q

    if (ws_size >= 3u * NEL * sizeof(ushort)) {
        // d_out bytes: [xbf (bf16 x)][qb (bf16 q)] — final GEMM overwrites.
        // wbf (bf16 QKV weights) parks at ab; attn overwrites ab only later.
        ushort* xbf = (ushort*)d_out;
        ushort* qb  = xbf + NEL;
        ushort* kb  = (ushort*)d_ws;
        ushort* vb  = kb + NEL;                  // holds VT [b,h,d,2048]
        ushort* ab  = vb + NEL;
        ushort* wbf = ab;                        // 3*262144 ushorts = 1.5 MB
        hipLaunchKernelGGL(cvt_bf16, dim3((int)(NEL / (256 * 8))), dim3(256), 0, stream,
                           x, xbf, (int)NEL);
        hipLaunchKernelGGL(cvt_w3, dim3(384), dim3(256), 0, stream, Wq, Wk, Wv, wbf);
        hipLaunchKernelGGL(gemm_qkv3, dim3(64, 12), dim3(256), 0, stream,
                           xbf, wbf, qscale, qb, kb, vb);
        hipLaunchKernelGGL(attn_kernel, dim3(16, 32), dim3(256), 0, stream, qb, kb, vb, ab);
        hipLaunchKernelGGL(gemm_out, dim3(64, 4), dim3(256), 0, stream, ab, Wp, bp, out);
    } else {
        // per-batch fallback: ws need = 3 * NELB * 2 = 6.3 MB
        ushort* kb = (ushort*)d_ws;
        ushort* vb = kb + NELB;
        ushort* ab = vb + NELB;
        ushort* wbf = ab;                        // 1.5 MB <= 2 MB slice
        for (int b = 0; b < 4; ++b) {
            const float* xb = x + (size_t)b * 2048u * 512u;
            float* ob = out + (size_t)b * 2048u * 512u;
            ushort* xbf = (ushort*)ob;           // batch slice: [xbf][qb]
            ushort* qb  = xbf + NELB;
            hipLaunchKernelGGL(cvt_bf16, dim3((int)(NELB / (256 * 8))), dim3(256), 0, stream,
                               xb, xbf, (int)NELB);
            hipLaunchKernelGGL(cvt_w3, dim3(384), dim3(256), 0, stream, Wq, Wk, Wv, wbf);
            hipLaunchKernelGGL(gemm_qkv3, dim3(16, 12), dim3(256), 0, stream,
                               xbf, wbf, qscale, qb, kb, vb);
            hipLaunchKernelGGL(attn_kernel, dim3(16, 8), dim3(256), 0, stream, qb, kb, vb, ab);
            hipLaunchKernelGGL(gemm_out, dim3(16, 4), dim3(256), 0, stream, ab, Wp, bp, ob);
        }
    }
}